// Round 15
// baseline (67.018 us; speedup 1.0000x reference)
//
#include <hip/hip_runtime.h>
#include <math.h>

// Problem constants
#define K_CODES 1024
#define C_DIM   128
#define HW      4096          // 64*64
#define CHW     (C_DIM*HW)    // per-batch stride in x
#define N_POS   65536         // 16*64*64
#define Q_ELEMS 8388608       // 16*128*64*64

// ws layout (byte offsets).
#define WS_S    0             // float: sum of sqrt(d2min)
#define WS_C2   256           // float[1024]: ||c_k||^2
#define WS_IDX  8192          // int[65536]: final argmin index per position

// d_out scratch (overwritten later; stream-ordered, safe):
//   offset 0: bf16 codebook (256 KB), row k at k*256B, granule-col j holds
//   channels of granule (j ^ (k&7)) -> linear global_load_lds staging +
//   swizzled ds_read_b128 A-frags. This region == q's (b=0, c<16) slice,
//   so b=0 blocks skip the fused q-store (write_q0 covers batch 0 after).

typedef __attribute__((ext_vector_type(8))) short short8;   // 8 bf16 (4 VGPRs)
typedef __attribute__((ext_vector_type(4))) float f32x4;    // MFMA acc

__device__ __forceinline__ unsigned short f2bf(float f) {   // fp32 -> bf16 RNE
    unsigned u = __float_as_uint(f);
    u += 0x7FFFu + ((u >> 16) & 1u);
    return (unsigned short)(u >> 16);
}

// async global->LDS, 16B per lane; LDS dst = wave-uniform base (+lane*16 by HW)
__device__ __forceinline__ void gll16(const void* g, void* l) {
    __builtin_amdgcn_global_load_lds(
        (const __attribute__((address_space(1))) void*)g,
        (__attribute__((address_space(3))) void*)l, 16, 0, 0);
}

// ---------------------------------------------------------------------------
// Kernel 1: prep. 256 blocks x 256 thr (4 waves), one code row per wave --
// per-row math bit-identical to the original 1024x64 version. (R19)
// ---------------------------------------------------------------------------
__global__ __launch_bounds__(256) void prep_kernel(const float* __restrict__ cb,
                                                   float* __restrict__ ws,
                                                   unsigned short* __restrict__ cbbf) {
    __shared__ __align__(16) unsigned short srow[4][128];
    int t = threadIdx.x;
    int w = t >> 6;                            // wave -> row within block
    int l = t & 63;
    int k = blockIdx.x * 4 + w;                // code row
    if (blockIdx.x == 0 && t == 0) *(float*)((char*)ws + WS_S) = 0.f;
    float v1 = cb[k * C_DIM + l];
    float v2 = cb[k * C_DIM + 64 + l];
    int c1 = l, c2 = 64 + l;
    srow[w][(((c1 >> 3) ^ (k & 7)) << 3) | (c1 & 7)] = f2bf(v1);
    srow[w][(((c2 >> 3) ^ (k & 7)) << 3) | (c2 & 7)] = f2bf(v2);
    float ss = v1 * v1 + v2 * v2;
    #pragma unroll
    for (int off = 32; off > 0; off >>= 1) ss += __shfl_down(ss, off);
    if (l == 0) ((float*)((char*)ws + WS_C2))[k] = ss;
    __syncthreads();
    if (l < 16) ((uint4*)cbbf)[k * 16 + l] = ((const uint4*)srow[w])[l];
}

// ---------------------------------------------------------------------------
// Kernel 2: fused VQ. R21 = R20 (counted-vmcnt pipeline; 65.15 total,
// absmax 0.0) with the pipeline FINISHED:
//  - c2 OUT OF VMEM: each wave byte-copies its 256-float c2 quarter into
//    LDS once in the prologue (1 gll16 -> bit-identical); the loop reads it
//    via broadcast ds_read. Loop VMEM = staging only -> exact gates.
//  - 3-DEEP staging: 4 buffers, stage chunk i+3 at iter i (~2.5 chunk-
//    periods of lead). Gates: vmcnt(12) for i<=12 (12 = 3 newer chunks x 4
//    loads; in-order retirement => chunk i landed), then 8/4/0 on the tail.
//  - xbuf aliases cbuf[3] (dead until chunk 3 staged at iter 0, after the
//    xf-read barrier). LDS 53.8 -> ~74 KB -- free per the R15/R20 evidence
//    that co-residency is pinned regardless.
// Buffer-reuse hazard: at iter i, buffer (i+3)%4 holds chunk i-1, whose
// ds_reads retired before the pre-stage lgkmcnt(0). Epilogue math byte-
// identical to R14/R20 (absmax-verified); c2 byte-copied; order unchanged.
// ---------------------------------------------------------------------------
__global__ __launch_bounds__(256, 2) void vq_mfma(const float* __restrict__ x,
                                                  const float* __restrict__ cb,
                                                  const unsigned short* __restrict__ cbbf,
                                                  const float* __restrict__ c2w,
                                                  int* __restrict__ idxw,
                                                  float* __restrict__ Sw,
                                                  float* __restrict__ out) {
    __shared__ __align__(16) unsigned short cbuf[4][4][2048]; // 4 x 16 KB
    __shared__ __align__(16) float c2s[1024];                 // 4 KB
    __shared__ float mbuf[4][4][16][3];                       // 3 KB
    __shared__ float nbuf[4][64];                             // 1 KB norms
    __shared__ int ibuf[64];                                  // 256 B

    const int t  = threadIdx.x;
    const int w  = t >> 6;                      // wave 0..3 = code quarter
    const int ln = t & 63;
    const int lp = ln & 15;                     // position lane (n index)
    const int q  = ln >> 4;                     // quad 0..3 (k sub-range)
    const int bid = blockIdx.x;
    const int b   = bid >> 6;                   // batch (64 blocks per image)
    const int s0  = (bid & 63) << 6;            // 64-position tile start

    // wave's quarter of the pre-swizzled bf16 codebook (64 KB)
    const char* gq = (const char*)cbbf + (w << 16);

    { // stage chunks 0,1,2 -> buffers 0,1,2 + this wave's c2 quarter NOW;
      // latency hides under the x-prologue (prologue barrier drains vmcnt)
        const char* gs = gq + (ln << 4);
        #pragma unroll
        for (int c = 0; c < 3; ++c) {
            char* lc = (char*)&cbuf[c][w][0];
            #pragma unroll
            for (int r = 0; r < 4; ++r)
                gll16(gs + c * 4096 + r * 1024, lc + r * 1024);
        }
        gll16((const char*)c2w + (w << 10) + (ln << 4), (char*)&c2s[w << 8]);
    }

    // ---- x-prologue: ONE coalesced load + convert per value, shared via
    //      LDS transpose buffer (aliases cbuf[3]; dead until chunk-3) ----
    unsigned short* xbuf = &cbuf[3][0][0];       // 64 pos x 128 ch bf16, 16 KB
    {
        float ssp = 0.f;
        const float* xgp = x + b * CHW + (w * 32) * HW + s0 + ln;
        #pragma unroll
        for (int g = 0; g < 4; ++g) {            // granule = 8 channels, 16B
            union { short8 v; unsigned short u[8]; } fu;
            #pragma unroll
            for (int j = 0; j < 8; ++j) {
                float vv = xgp[(g * 8 + j) * HW];   // 256B coalesced segment
                ssp = fmaf(vv, vv, ssp);
                fu.u[j] = f2bf(vv);
            }
            int col = (w * 4 + g) ^ (ln & 7);    // same swizzle family as cb
            *(short8*)(xbuf + ln * 128 + col * 8) = fu.v;
        }
        nbuf[w][ln] = ssp;                       // partial over w's 32 ch
    }
    __syncthreads();                             // xbuf + nbuf + c2s complete

    // norms: fixed pairwise order over the 4 wave-partials
    float r2v[4];
    #pragma unroll
    for (int pt = 0; pt < 4; ++pt) {
        const int pos = pt * 16 + lp;
        float s01 = nbuf[0][pos] + nbuf[1][pos];
        float s23 = nbuf[2][pos] + nbuf[3][pos];
        float s   = s01 + s23;
        r2v[pt] = -2.0f / fmaxf(sqrtf(s), 1e-12f);  // F.normalize eps
    }

    // fragments: identical layout/order (bit-identical bf16)
    short8 xf[4][4];
    #pragma unroll
    for (int pt = 0; pt < 4; ++pt)
        #pragma unroll
        for (int cs = 0; cs < 4; ++cs) {
            int col = (4 * cs + q) ^ (lp & 7);   // (pt*16+lp)&7 == lp&7
            xf[pt][cs] = *(const short8*)(xbuf + (pt * 16 + lp) * 128 + col * 8);
        }
    asm volatile("s_waitcnt lgkmcnt(0)" ::: "memory");  // xf live in regs
    __builtin_amdgcn_sched_barrier(0);
    __syncthreads();                             // xbuf (buf 3) free for ch3

    const float FMAX = __uint_as_float(0x7F7FFFFFu);
    float m1[4] = {FMAX, FMAX, FMAX, FMAX};
    float m2[4] = {FMAX, FMAX, FMAX, FMAX};
    float m3[4] = {FMAX, FMAX, FMAX, FMAX};

    for (int i = 0; i < 16; ++i) {              // 16 chunks x 16 codes
        const int k0 = (w << 8) + (i << 4);

        if (i <= 12) {                           // stage chunk i+3 (private)
            asm volatile("s_waitcnt lgkmcnt(0)" ::: "memory");
            const char* gs = gq + (i + 3) * 4096 + (ln << 4);
            char* ld = (char*)&cbuf[(i + 3) & 3][w][0];
            #pragma unroll
            for (int r = 0; r < 4; ++r) gll16(gs + r * 1024, ld + r * 1024);
        }

        // counted gate: chunk i landed; up to 3 younger chunks stay in flight
        if (i <= 12)      asm volatile("s_waitcnt vmcnt(12)" ::: "memory");
        else if (i == 13) asm volatile("s_waitcnt vmcnt(8)" ::: "memory");
        else if (i == 14) asm volatile("s_waitcnt vmcnt(4)" ::: "memory");
        else              asm volatile("s_waitcnt vmcnt(0)" ::: "memory");
        __builtin_amdgcn_sched_barrier(0);

        // c2 from LDS (broadcast read; byte-copied from c2w -> bit-identical)
        float4 c2vv = *(const float4*)(&c2s[(w << 8) + (i << 4) + 4 * q]);

        const unsigned short* cbp = &cbuf[i & 3][w][0];

        f32x4 acc[4];
        #pragma unroll
        for (int pt = 0; pt < 4; ++pt) acc[pt] = 0;

        #pragma unroll
        for (int cs = 0; cs < 4; ++cs) {
            // A[m=lp][k=32cs+8q+j]; row-within-chunk = lp, swizzled granule
            int g = lp * 16 + ((4 * cs + q) ^ (lp & 7));
            short8 ah = *(const short8*)(cbp + g * 8);
            #pragma unroll
            for (int pt = 0; pt < 4; ++pt)
                acc[pt] = __builtin_amdgcn_mfma_f32_16x16x32_bf16(
                    ah, xf[pt][cs], acc[pt], 0, 0, 0);
        }

        // ---- epilogue: 16 scores/lane (4pt x 4reg) -- R14-verified math ----
        {
            float c2a[4] = {c2vv.x, c2vv.y, c2vv.z, c2vv.w};
            const int kb0 = k0 + 4 * q;
            #pragma unroll
            for (int pt = 0; pt < 4; ++pt) {
                #pragma unroll
                for (int reg = 0; reg < 4; ++reg) {
                    float s = fmaf(r2v[pt], acc[pt][reg], c2a[reg]);
                    unsigned pb = (__float_as_uint(s) & 0xFFFFFC00u) |
                                  (unsigned)(kb0 + reg);
                    float u  = __uint_as_float(pb);
                    float t3 = __builtin_amdgcn_fmed3f(m2[pt], m3[pt], u);
                    float t2 = __builtin_amdgcn_fmed3f(m1[pt], m2[pt], u);
                    m1[pt] = fminf(m1[pt], u); m2[pt] = t2; m3[pt] = t3;
                }
            }
        }
    }

    // ---- merge chains across the 4 quad-lanes (butterfly, all 4 pt) ----
    #pragma unroll
    for (int d = 16; d <= 32; d <<= 1) {
        #pragma unroll
        for (int pt = 0; pt < 4; ++pt) {
            float o1 = __shfl_xor(m1[pt], d), o2 = __shfl_xor(m2[pt], d),
                  o3 = __shfl_xor(m3[pt], d);
            float u, t2, t3;
            u = o1; t3 = __builtin_amdgcn_fmed3f(m2[pt], m3[pt], u);
            t2 = __builtin_amdgcn_fmed3f(m1[pt], m2[pt], u);
            m1[pt] = fminf(m1[pt], u); m2[pt] = t2; m3[pt] = t3;
            u = o2; t3 = __builtin_amdgcn_fmed3f(m2[pt], m3[pt], u);
            t2 = __builtin_amdgcn_fmed3f(m1[pt], m2[pt], u);
            m1[pt] = fminf(m1[pt], u); m2[pt] = t2; m3[pt] = t3;
            u = o3; t3 = __builtin_amdgcn_fmed3f(m2[pt], m3[pt], u);
            t2 = __builtin_amdgcn_fmed3f(m1[pt], m2[pt], u);
            m1[pt] = fminf(m1[pt], u); m2[pt] = t2; m3[pt] = t3;
        }
    }

    // publish all 4 per-quarter chains
    if (ln < 16) {
        #pragma unroll
        for (int pt = 0; pt < 4; ++pt) {
            mbuf[w][pt][lp][0] = m1[pt];
            mbuf[w][pt][lp][1] = m2[pt];
            mbuf[w][pt][lp][2] = m3[pt];
        }
    }

    // ---- hoisted rescore x-reload (bit-identical; hides under barrier) ----
    float xr2[2][32];
    if (w < 2) {
        #pragma unroll
        for (int ptl = 0; ptl < 2; ++ptl) {
            const int pt = 2 * w + ptl;
            const float* xgp = x + b * CHW + s0 + pt * 16 + lp;
            #pragma unroll
            for (int cs = 0; cs < 4; ++cs)
                #pragma unroll
                for (int j = 0; j < 8; ++j)
                    xr2[ptl][cs * 8 + j] = xgp[(32 * cs + 8 * q + j) * HW];
        }
    }
    __syncthreads();

    // ---- rescore: wave 0 -> positions 0-31 (pt 0,1), wave 1 -> 32-63 ----
    if (w < 2) {
        float lsum = 0.f;
        #pragma unroll
        for (int ptl = 0; ptl < 2; ++ptl) {
            const int pt = 2 * w + ptl;
            // merge the 4 quarters' chains (fixed order; unique top-3 set)
            float M1 = FMAX, M2 = FMAX, M3 = FMAX;
            #pragma unroll
            for (int ww = 0; ww < 4; ++ww)
                #pragma unroll
                for (int c = 0; c < 3; ++c) {
                    float u  = mbuf[ww][pt][lp][c];
                    float t3 = __builtin_amdgcn_fmed3f(M2, M3, u);
                    float t2 = __builtin_amdgcn_fmed3f(M1, M2, u);
                    M1 = fminf(M1, u); M2 = t2; M3 = t3;
                }
            int ks[3] = {(int)(__float_as_uint(M1) & 1023u),
                         (int)(__float_as_uint(M2) & 1023u),
                         (int)(__float_as_uint(M3) & 1023u)};

            const float* xr = xr2[ptl];          // preloaded, bit-identical

            // exact fp32 rescore of the 3 candidates (same order as R4-R20)
            float dots[3];
            #pragma unroll
            for (int jj = 0; jj < 3; ++jj) {
                const float* crow = cb + ks[jj] * C_DIM + 8 * q;
                float p = 0.f;
                #pragma unroll
                for (int cs = 0; cs < 4; ++cs) {
                    float4 a0 = *(const float4*)(crow + 32 * cs);
                    float4 a1 = *(const float4*)(crow + 32 * cs + 4);
                    p = fmaf(xr[cs*8+0], a0.x, p); p = fmaf(xr[cs*8+1], a0.y, p);
                    p = fmaf(xr[cs*8+2], a0.z, p); p = fmaf(xr[cs*8+3], a0.w, p);
                    p = fmaf(xr[cs*8+4], a1.x, p); p = fmaf(xr[cs*8+5], a1.y, p);
                    p = fmaf(xr[cs*8+6], a1.z, p); p = fmaf(xr[cs*8+7], a1.w, p);
                }
                p += __shfl_xor(p, 16);
                p += __shfl_xor(p, 32);
                dots[jj] = p;
            }
            float sb = fmaf(r2v[pt], dots[0], c2w[ks[0]]); int kb = ks[0];
            float s2 = fmaf(r2v[pt], dots[1], c2w[ks[1]]);
            if (s2 < sb || (s2 == sb && ks[1] < kb)) { sb = s2; kb = ks[1]; }
            float s3 = fmaf(r2v[pt], dots[2], c2w[ks[2]]);
            if (s3 < sb || (s3 == sb && ks[2] < kb)) { sb = s3; kb = ks[2]; }

            if (ln < 16) {
                idxw[bid * 64 + pt * 16 + lp] = kb;
                ibuf[pt * 16 + lp] = kb;         // publish for fused store
            }
            lsum += sqrtf(fmaxf(1.0f + sb, 0.f));   // z2 == 1 after normalize
        }
        // each position counted by its 4 q-lanes -> scale 0.25
        #pragma unroll
        for (int off = 32; off > 0; off >>= 1) lsum += __shfl_down(lsum, off);
        if (ln == 0) atomicAdd(Sw, 0.25f * lsum);
    }

    // ---- fused q-store (b>0; batch 0's region aliases cbbf -> write_q0) ----
    __syncthreads();                             // ibuf visible to all waves
    if (b != 0) {
        const int row = ibuf[ln];                // position s0+ln's code
        const float4* cbr = (const float4*)cb + row * 32;
        float* ob = out + b * CHW + s0 + ln;
        #pragma unroll
        for (int c4 = w * 8; c4 < w * 8 + 8; ++c4) {   // wave w: 32 channels
            float4 v = cbr[c4];                  // 16B gather, L2-hot
            float* o = ob + (c4 * 4) * HW;
            o[0]      = v.x;                     // each store: 64 lanes x 4B
            o[HW]     = v.y;                     //  = coalesced 256B segment
            o[2 * HW] = v.z;
            o[3 * HW] = v.w;
        }
    }
}

// ---------------------------------------------------------------------------
// Kernel 3: batch-0 scatter (region was cbbf scratch during vq) + losses.
// ---------------------------------------------------------------------------
__global__ void write_q0(const float* __restrict__ cb,
                         const int* __restrict__ idxw,
                         const float* __restrict__ ws,
                         float* __restrict__ out) {
    int id = blockIdx.x * 256 + threadIdx.x;   // 131072 = 4096 * 32
    int s  = id & 4095;                        // spatial (lanes consecutive)
    int c4 = id >> 12;                         // channel quad 0..31
    int row = idxw[s];                         // batch 0 -> p == s
    float4 v = ((const float4*)cb)[row * 32 + c4];   // 16B gather, L2-hot
    float* o = out + (c4 * 4) * HW + s;        // b = 0
    o[0]      = v.x;
    o[HW]     = v.y;
    o[2 * HW] = v.z;
    o[3 * HW] = v.w;
    if (id == 0) {                             // loss finalize (after vq)
        float S = *(const float*)((const char*)ws + WS_S);
        float m = S / (float)N_POS;
        out[Q_ELEMS]     = 0.25f * m;
        out[Q_ELEMS + 1] = m;
    }
}

extern "C" void kernel_launch(void* const* d_in, const int* in_sizes, int n_in,
                              void* d_out, int out_size, void* d_ws, size_t ws_size,
                              hipStream_t stream) {
    const float* x  = (const float*)d_in[0];   // [16,128,64,64]
    const float* cb = (const float*)d_in[1];   // [1024,128]
    float* out = (float*)d_out;
    float* ws  = (float*)d_ws;

    const float* c2w = (const float*)((const char*)d_ws + WS_C2);
    int*  idxw = (int*)((char*)d_ws + WS_IDX);
    float* Sw  = (float*)((char*)d_ws + WS_S);
    unsigned short* cbbf = (unsigned short*)d_out;   // scratch in d_out

    prep_kernel<<<K_CODES / 4, 256, 0, stream>>>(cb, ws, cbbf);
    vq_mfma    <<<N_POS / 64, 256, 0, stream>>>(x, cb, cbbf, c2w, idxw, Sw, out);
    write_q0   <<<512, 256, 0, stream>>>(cb, idxw, ws, out);
}

// Round 16
// 66.315 us; speedup vs baseline: 1.0106x; 1.0106x over previous
//
#include <hip/hip_runtime.h>
#include <math.h>

// Problem constants
#define K_CODES 1024
#define C_DIM   128
#define HW      4096          // 64*64
#define CHW     (C_DIM*HW)    // per-batch stride in x
#define N_POS   65536         // 16*64*64
#define Q_ELEMS 8388608       // 16*128*64*64

// ws layout (byte offsets).
#define WS_S    0             // float: sum of sqrt(d2min)
#define WS_C2   256           // float[1024]: ||c_k||^2
#define WS_IDX  8192          // int[65536]: final argmin index per position

// d_out scratch (overwritten later; stream-ordered, safe):
//   offset 0: bf16 codebook (256 KB), row k at k*256B, granule-col j holds
//   channels of granule (j ^ (k&7)) -> linear global_load_lds staging +
//   swizzled ds_read_b128 A-frags. This region == q's (b=0, c<16) slice,
//   so b=0 blocks skip the fused q-store (write_q0 covers batch 0 after).

typedef __attribute__((ext_vector_type(8))) short short8;   // 8 bf16 (4 VGPRs)
typedef __attribute__((ext_vector_type(4))) float f32x4;    // MFMA acc

__device__ __forceinline__ unsigned short f2bf(float f) {   // fp32 -> bf16 RNE
    unsigned u = __float_as_uint(f);
    u += 0x7FFFu + ((u >> 16) & 1u);
    return (unsigned short)(u >> 16);
}

// async global->LDS, 16B per lane; LDS dst = wave-uniform base (+lane*16 by HW)
__device__ __forceinline__ void gll16(const void* g, void* l) {
    __builtin_amdgcn_global_load_lds(
        (const __attribute__((address_space(1))) void*)g,
        (__attribute__((address_space(3))) void*)l, 16, 0, 0);
}

// ---------------------------------------------------------------------------
// Kernel 1: prep. 256 blocks x 256 thr (4 waves), one code row per wave --
// per-row math bit-identical to the original 1024x64 version. (R19)
// ---------------------------------------------------------------------------
__global__ __launch_bounds__(256) void prep_kernel(const float* __restrict__ cb,
                                                   float* __restrict__ ws,
                                                   unsigned short* __restrict__ cbbf) {
    __shared__ __align__(16) unsigned short srow[4][128];
    int t = threadIdx.x;
    int w = t >> 6;                            // wave -> row within block
    int l = t & 63;
    int k = blockIdx.x * 4 + w;                // code row
    if (blockIdx.x == 0 && t == 0) *(float*)((char*)ws + WS_S) = 0.f;
    float v1 = cb[k * C_DIM + l];
    float v2 = cb[k * C_DIM + 64 + l];
    int c1 = l, c2 = 64 + l;
    srow[w][(((c1 >> 3) ^ (k & 7)) << 3) | (c1 & 7)] = f2bf(v1);
    srow[w][(((c2 >> 3) ^ (k & 7)) << 3) | (c2 & 7)] = f2bf(v2);
    float ss = v1 * v1 + v2 * v2;
    #pragma unroll
    for (int off = 32; off > 0; off >>= 1) ss += __shfl_down(ss, off);
    if (l == 0) ((float*)((char*)ws + WS_C2))[k] = ss;
    __syncthreads();
    if (l < 16) ((uint4*)cbbf)[k * 16 + l] = ((const uint4*)srow[w])[l];
}

// ---------------------------------------------------------------------------
// Kernel 2: fused VQ. R22 = single-variable rollback from R21: keep c2-in-
// LDS (byte-copied via 1 gll16/wave in the prologue -> bit-identical;
// absmax-verified in R21), REVERT staging depth to R20's proven 2-deep
// (3 buffers, stage chunk i+2 at iter i). With c2 out of VMEM the loop's
// VMEM stream is purely staging, so the counted gates are exact AND the
// epilogue has no compiler-inserted VMEM wait at all (R20 still partially
// drained at each c2 use): gates vmcnt(8) for i<14 (8 = ch_{i+1} 4 +
// ch_{i+2} 4 newer loads; in-order retirement => chunk i landed), then
// vmcnt(4) at i=14, vmcnt(0) at i=15. Buffer-reuse hazard: at iter i the
// stage target (i+2)%3 held chunk i-1, whose ds_reads retired before the
// pre-stage lgkmcnt(0). Everything else byte-identical to R20/R21
// (x-prologue dedup, wave-private scan, merge, hoisted rescore,
// fused q-store; absmax-0.0 lineage).
// ---------------------------------------------------------------------------
__global__ __launch_bounds__(256, 2) void vq_mfma(const float* __restrict__ x,
                                                  const float* __restrict__ cb,
                                                  const unsigned short* __restrict__ cbbf,
                                                  const float* __restrict__ c2w,
                                                  int* __restrict__ idxw,
                                                  float* __restrict__ Sw,
                                                  float* __restrict__ out) {
    __shared__ __align__(16) unsigned short cbuf[3][4][2048]; // 3 x 16 KB
    __shared__ __align__(16) float c2s[1024];                 // 4 KB
    __shared__ float mbuf[4][4][16][3];                       // 3 KB
    __shared__ float nbuf[4][64];                             // 1 KB norms
    __shared__ int ibuf[64];                                  // 256 B

    const int t  = threadIdx.x;
    const int w  = t >> 6;                      // wave 0..3 = code quarter
    const int ln = t & 63;
    const int lp = ln & 15;                     // position lane (n index)
    const int q  = ln >> 4;                     // quad 0..3 (k sub-range)
    const int bid = blockIdx.x;
    const int b   = bid >> 6;                   // batch (64 blocks per image)
    const int s0  = (bid & 63) << 6;            // 64-position tile start

    // wave's quarter of the pre-swizzled bf16 codebook (64 KB)
    const char* gq = (const char*)cbbf + (w << 16);

    { // stage chunks 0,1 -> buffers 0,1 + this wave's c2 quarter NOW;
      // latency hides under the x-prologue (prologue barrier drains vmcnt)
        const char* gs = gq + (ln << 4);
        char* l0 = (char*)&cbuf[0][w][0];
        char* l1 = (char*)&cbuf[1][w][0];
        #pragma unroll
        for (int r = 0; r < 4; ++r) gll16(gs + r * 1024, l0 + r * 1024);
        #pragma unroll
        for (int r = 0; r < 4; ++r) gll16(gs + 4096 + r * 1024, l1 + r * 1024);
        gll16((const char*)c2w + (w << 10) + (ln << 4), (char*)&c2s[w << 8]);
    }

    // ---- x-prologue: ONE coalesced load + convert per value, shared via
    //      LDS transpose buffer (aliases cbuf[2]; dead until chunk-2) ----
    unsigned short* xbuf = &cbuf[2][0][0];       // 64 pos x 128 ch bf16, 16 KB
    {
        float ssp = 0.f;
        const float* xgp = x + b * CHW + (w * 32) * HW + s0 + ln;
        #pragma unroll
        for (int g = 0; g < 4; ++g) {            // granule = 8 channels, 16B
            union { short8 v; unsigned short u[8]; } fu;
            #pragma unroll
            for (int j = 0; j < 8; ++j) {
                float vv = xgp[(g * 8 + j) * HW];   // 256B coalesced segment
                ssp = fmaf(vv, vv, ssp);
                fu.u[j] = f2bf(vv);
            }
            int col = (w * 4 + g) ^ (ln & 7);    // same swizzle family as cb
            *(short8*)(xbuf + ln * 128 + col * 8) = fu.v;
        }
        nbuf[w][ln] = ssp;                       // partial over w's 32 ch
    }
    __syncthreads();                             // xbuf + nbuf + c2s complete

    // norms: fixed pairwise order over the 4 wave-partials
    float r2v[4];
    #pragma unroll
    for (int pt = 0; pt < 4; ++pt) {
        const int pos = pt * 16 + lp;
        float s01 = nbuf[0][pos] + nbuf[1][pos];
        float s23 = nbuf[2][pos] + nbuf[3][pos];
        float s   = s01 + s23;
        r2v[pt] = -2.0f / fmaxf(sqrtf(s), 1e-12f);  // F.normalize eps
    }

    // fragments: identical layout/order (bit-identical bf16)
    short8 xf[4][4];
    #pragma unroll
    for (int pt = 0; pt < 4; ++pt)
        #pragma unroll
        for (int cs = 0; cs < 4; ++cs) {
            int col = (4 * cs + q) ^ (lp & 7);   // (pt*16+lp)&7 == lp&7
            xf[pt][cs] = *(const short8*)(xbuf + (pt * 16 + lp) * 128 + col * 8);
        }
    asm volatile("s_waitcnt lgkmcnt(0)" ::: "memory");  // xf live in regs
    __builtin_amdgcn_sched_barrier(0);
    __syncthreads();                             // xbuf (buf 2) free for ch2

    const float FMAX = __uint_as_float(0x7F7FFFFFu);
    float m1[4] = {FMAX, FMAX, FMAX, FMAX};
    float m2[4] = {FMAX, FMAX, FMAX, FMAX};
    float m3[4] = {FMAX, FMAX, FMAX, FMAX};

    for (int i = 0; i < 16; ++i) {              // 16 chunks x 16 codes
        const int k0 = (w << 8) + (i << 4);

        if (i < 14) {                            // stage chunk i+2 (private)
            asm volatile("s_waitcnt lgkmcnt(0)" ::: "memory");
            const char* gs = gq + (i + 2) * 4096 + (ln << 4);
            char* ld = (char*)&cbuf[(i + 2) % 3][w][0];
            #pragma unroll
            for (int r = 0; r < 4; ++r) gll16(gs + r * 1024, ld + r * 1024);
        }

        // counted gate: chunk i landed; ch_{i+1}, ch_{i+2} stay in flight
        if (i < 14)       asm volatile("s_waitcnt vmcnt(8)" ::: "memory");
        else if (i == 14) asm volatile("s_waitcnt vmcnt(4)" ::: "memory");
        else              asm volatile("s_waitcnt vmcnt(0)" ::: "memory");
        __builtin_amdgcn_sched_barrier(0);

        // c2 from LDS (broadcast read; byte-copied from c2w -> bit-identical)
        float4 c2vv = *(const float4*)(&c2s[(w << 8) + (i << 4) + 4 * q]);

        const unsigned short* cbp = &cbuf[i % 3][w][0];

        f32x4 acc[4];
        #pragma unroll
        for (int pt = 0; pt < 4; ++pt) acc[pt] = 0;

        #pragma unroll
        for (int cs = 0; cs < 4; ++cs) {
            // A[m=lp][k=32cs+8q+j]; row-within-chunk = lp, swizzled granule
            int g = lp * 16 + ((4 * cs + q) ^ (lp & 7));
            short8 ah = *(const short8*)(cbp + g * 8);
            #pragma unroll
            for (int pt = 0; pt < 4; ++pt)
                acc[pt] = __builtin_amdgcn_mfma_f32_16x16x32_bf16(
                    ah, xf[pt][cs], acc[pt], 0, 0, 0);
        }

        // ---- epilogue: 16 scores/lane (4pt x 4reg) -- R14-verified math ----
        {
            float c2a[4] = {c2vv.x, c2vv.y, c2vv.z, c2vv.w};
            const int kb0 = k0 + 4 * q;
            #pragma unroll
            for (int pt = 0; pt < 4; ++pt) {
                #pragma unroll
                for (int reg = 0; reg < 4; ++reg) {
                    float s = fmaf(r2v[pt], acc[pt][reg], c2a[reg]);
                    unsigned pb = (__float_as_uint(s) & 0xFFFFFC00u) |
                                  (unsigned)(kb0 + reg);
                    float u  = __uint_as_float(pb);
                    float t3 = __builtin_amdgcn_fmed3f(m2[pt], m3[pt], u);
                    float t2 = __builtin_amdgcn_fmed3f(m1[pt], m2[pt], u);
                    m1[pt] = fminf(m1[pt], u); m2[pt] = t2; m3[pt] = t3;
                }
            }
        }
    }

    // ---- merge chains across the 4 quad-lanes (butterfly, all 4 pt) ----
    #pragma unroll
    for (int d = 16; d <= 32; d <<= 1) {
        #pragma unroll
        for (int pt = 0; pt < 4; ++pt) {
            float o1 = __shfl_xor(m1[pt], d), o2 = __shfl_xor(m2[pt], d),
                  o3 = __shfl_xor(m3[pt], d);
            float u, t2, t3;
            u = o1; t3 = __builtin_amdgcn_fmed3f(m2[pt], m3[pt], u);
            t2 = __builtin_amdgcn_fmed3f(m1[pt], m2[pt], u);
            m1[pt] = fminf(m1[pt], u); m2[pt] = t2; m3[pt] = t3;
            u = o2; t3 = __builtin_amdgcn_fmed3f(m2[pt], m3[pt], u);
            t2 = __builtin_amdgcn_fmed3f(m1[pt], m2[pt], u);
            m1[pt] = fminf(m1[pt], u); m2[pt] = t2; m3[pt] = t3;
            u = o3; t3 = __builtin_amdgcn_fmed3f(m2[pt], m3[pt], u);
            t2 = __builtin_amdgcn_fmed3f(m1[pt], m2[pt], u);
            m1[pt] = fminf(m1[pt], u); m2[pt] = t2; m3[pt] = t3;
        }
    }

    // publish all 4 per-quarter chains
    if (ln < 16) {
        #pragma unroll
        for (int pt = 0; pt < 4; ++pt) {
            mbuf[w][pt][lp][0] = m1[pt];
            mbuf[w][pt][lp][1] = m2[pt];
            mbuf[w][pt][lp][2] = m3[pt];
        }
    }

    // ---- hoisted rescore x-reload (bit-identical; hides under barrier) ----
    float xr2[2][32];
    if (w < 2) {
        #pragma unroll
        for (int ptl = 0; ptl < 2; ++ptl) {
            const int pt = 2 * w + ptl;
            const float* xgp = x + b * CHW + s0 + pt * 16 + lp;
            #pragma unroll
            for (int cs = 0; cs < 4; ++cs)
                #pragma unroll
                for (int j = 0; j < 8; ++j)
                    xr2[ptl][cs * 8 + j] = xgp[(32 * cs + 8 * q + j) * HW];
        }
    }
    __syncthreads();

    // ---- rescore: wave 0 -> positions 0-31 (pt 0,1), wave 1 -> 32-63 ----
    if (w < 2) {
        float lsum = 0.f;
        #pragma unroll
        for (int ptl = 0; ptl < 2; ++ptl) {
            const int pt = 2 * w + ptl;
            // merge the 4 quarters' chains (fixed order; unique top-3 set)
            float M1 = FMAX, M2 = FMAX, M3 = FMAX;
            #pragma unroll
            for (int ww = 0; ww < 4; ++ww)
                #pragma unroll
                for (int c = 0; c < 3; ++c) {
                    float u  = mbuf[ww][pt][lp][c];
                    float t3 = __builtin_amdgcn_fmed3f(M2, M3, u);
                    float t2 = __builtin_amdgcn_fmed3f(M1, M2, u);
                    M1 = fminf(M1, u); M2 = t2; M3 = t3;
                }
            int ks[3] = {(int)(__float_as_uint(M1) & 1023u),
                         (int)(__float_as_uint(M2) & 1023u),
                         (int)(__float_as_uint(M3) & 1023u)};

            const float* xr = xr2[ptl];          // preloaded, bit-identical

            // exact fp32 rescore of the 3 candidates (same order as R4-R21)
            float dots[3];
            #pragma unroll
            for (int jj = 0; jj < 3; ++jj) {
                const float* crow = cb + ks[jj] * C_DIM + 8 * q;
                float p = 0.f;
                #pragma unroll
                for (int cs = 0; cs < 4; ++cs) {
                    float4 a0 = *(const float4*)(crow + 32 * cs);
                    float4 a1 = *(const float4*)(crow + 32 * cs + 4);
                    p = fmaf(xr[cs*8+0], a0.x, p); p = fmaf(xr[cs*8+1], a0.y, p);
                    p = fmaf(xr[cs*8+2], a0.z, p); p = fmaf(xr[cs*8+3], a0.w, p);
                    p = fmaf(xr[cs*8+4], a1.x, p); p = fmaf(xr[cs*8+5], a1.y, p);
                    p = fmaf(xr[cs*8+6], a1.z, p); p = fmaf(xr[cs*8+7], a1.w, p);
                }
                p += __shfl_xor(p, 16);
                p += __shfl_xor(p, 32);
                dots[jj] = p;
            }
            float sb = fmaf(r2v[pt], dots[0], c2w[ks[0]]); int kb = ks[0];
            float s2 = fmaf(r2v[pt], dots[1], c2w[ks[1]]);
            if (s2 < sb || (s2 == sb && ks[1] < kb)) { sb = s2; kb = ks[1]; }
            float s3 = fmaf(r2v[pt], dots[2], c2w[ks[2]]);
            if (s3 < sb || (s3 == sb && ks[2] < kb)) { sb = s3; kb = ks[2]; }

            if (ln < 16) {
                idxw[bid * 64 + pt * 16 + lp] = kb;
                ibuf[pt * 16 + lp] = kb;         // publish for fused store
            }
            lsum += sqrtf(fmaxf(1.0f + sb, 0.f));   // z2 == 1 after normalize
        }
        // each position counted by its 4 q-lanes -> scale 0.25
        #pragma unroll
        for (int off = 32; off > 0; off >>= 1) lsum += __shfl_down(lsum, off);
        if (ln == 0) atomicAdd(Sw, 0.25f * lsum);
    }

    // ---- fused q-store (b>0; batch 0's region aliases cbbf -> write_q0) ----
    __syncthreads();                             // ibuf visible to all waves
    if (b != 0) {
        const int row = ibuf[ln];                // position s0+ln's code
        const float4* cbr = (const float4*)cb + row * 32;
        float* ob = out + b * CHW + s0 + ln;
        #pragma unroll
        for (int c4 = w * 8; c4 < w * 8 + 8; ++c4) {   // wave w: 32 channels
            float4 v = cbr[c4];                  // 16B gather, L2-hot
            float* o = ob + (c4 * 4) * HW;
            o[0]      = v.x;                     // each store: 64 lanes x 4B
            o[HW]     = v.y;                     //  = coalesced 256B segment
            o[2 * HW] = v.z;
            o[3 * HW] = v.w;
        }
    }
}

// ---------------------------------------------------------------------------
// Kernel 3: batch-0 scatter (region was cbbf scratch during vq) + losses.
// ---------------------------------------------------------------------------
__global__ void write_q0(const float* __restrict__ cb,
                         const int* __restrict__ idxw,
                         const float* __restrict__ ws,
                         float* __restrict__ out) {
    int id = blockIdx.x * 256 + threadIdx.x;   // 131072 = 4096 * 32
    int s  = id & 4095;                        // spatial (lanes consecutive)
    int c4 = id >> 12;                         // channel quad 0..31
    int row = idxw[s];                         // batch 0 -> p == s
    float4 v = ((const float4*)cb)[row * 32 + c4];   // 16B gather, L2-hot
    float* o = out + (c4 * 4) * HW + s;        // b = 0
    o[0]      = v.x;
    o[HW]     = v.y;
    o[2 * HW] = v.z;
    o[3 * HW] = v.w;
    if (id == 0) {                             // loss finalize (after vq)
        float S = *(const float*)((const char*)ws + WS_S);
        float m = S / (float)N_POS;
        out[Q_ELEMS]     = 0.25f * m;
        out[Q_ELEMS + 1] = m;
    }
}

extern "C" void kernel_launch(void* const* d_in, const int* in_sizes, int n_in,
                              void* d_out, int out_size, void* d_ws, size_t ws_size,
                              hipStream_t stream) {
    const float* x  = (const float*)d_in[0];   // [16,128,64,64]
    const float* cb = (const float*)d_in[1];   // [1024,128]
    float* out = (float*)d_out;
    float* ws  = (float*)d_ws;

    const float* c2w = (const float*)((const char*)d_ws + WS_C2);
    int*  idxw = (int*)((char*)d_ws + WS_IDX);
    float* Sw  = (float*)((char*)d_ws + WS_S);
    unsigned short* cbbf = (unsigned short*)d_out;   // scratch in d_out

    prep_kernel<<<K_CODES / 4, 256, 0, stream>>>(cb, ws, cbbf);
    vq_mfma    <<<N_POS / 64, 256, 0, stream>>>(x, cb, cbbf, c2w, idxw, Sw, out);
    write_q0   <<<512, 256, 0, stream>>>(cb, idxw, ws, out);
}

// Round 17
// 64.710 us; speedup vs baseline: 1.0357x; 1.0248x over previous
//
#include <hip/hip_runtime.h>
#include <math.h>

// Problem constants
#define K_CODES 1024
#define C_DIM   128
#define HW      4096          // 64*64
#define CHW     (C_DIM*HW)    // per-batch stride in x
#define N_POS   65536         // 16*64*64
#define Q_ELEMS 8388608       // 16*128*64*64

// ws layout (byte offsets).
#define WS_S    0             // float: sum of sqrt(d2min)
#define WS_C2   256           // float[1024]: ||c_k||^2
#define WS_IDX  8192          // int[65536]: final argmin index per position

// d_out scratch (overwritten later; stream-ordered, safe):
//   offset 0: bf16 codebook (256 KB), row k at k*256B, granule-col j holds
//   channels of granule (j ^ (k&7)) -> linear global_load_lds staging +
//   swizzled ds_read_b128 A-frags. This region == q's (b=0, c<16) slice,
//   so b=0 blocks skip the fused q-store (write_q0 covers batch 0 after).

typedef __attribute__((ext_vector_type(8))) short short8;   // 8 bf16 (4 VGPRs)
typedef __attribute__((ext_vector_type(4))) float f32x4;    // MFMA acc

__device__ __forceinline__ unsigned short f2bf(float f) {   // fp32 -> bf16 RNE
    unsigned u = __float_as_uint(f);
    u += 0x7FFFu + ((u >> 16) & 1u);
    return (unsigned short)(u >> 16);
}

// async global->LDS, 16B per lane; LDS dst = wave-uniform base (+lane*16 by HW)
__device__ __forceinline__ void gll16(const void* g, void* l) {
    __builtin_amdgcn_global_load_lds(
        (const __attribute__((address_space(1))) void*)g,
        (__attribute__((address_space(3))) void*)l, 16, 0, 0);
}

// ---------------------------------------------------------------------------
// Kernel 1: prep. 256 blocks x 256 thr (4 waves), one code row per wave --
// per-row math bit-identical to the original 1024x64 version. (R19)
// ---------------------------------------------------------------------------
__global__ __launch_bounds__(256) void prep_kernel(const float* __restrict__ cb,
                                                   float* __restrict__ ws,
                                                   unsigned short* __restrict__ cbbf) {
    __shared__ __align__(16) unsigned short srow[4][128];
    int t = threadIdx.x;
    int w = t >> 6;                            // wave -> row within block
    int l = t & 63;
    int k = blockIdx.x * 4 + w;                // code row
    if (blockIdx.x == 0 && t == 0) *(float*)((char*)ws + WS_S) = 0.f;
    float v1 = cb[k * C_DIM + l];
    float v2 = cb[k * C_DIM + 64 + l];
    int c1 = l, c2 = 64 + l;
    srow[w][(((c1 >> 3) ^ (k & 7)) << 3) | (c1 & 7)] = f2bf(v1);
    srow[w][(((c2 >> 3) ^ (k & 7)) << 3) | (c2 & 7)] = f2bf(v2);
    float ss = v1 * v1 + v2 * v2;
    #pragma unroll
    for (int off = 32; off > 0; off >>= 1) ss += __shfl_down(ss, off);
    if (l == 0) ((float*)((char*)ws + WS_C2))[k] = ss;
    __syncthreads();
    if (l < 16) ((uint4*)cbbf)[k * 16 + l] = ((const uint4*)srow[w])[l];
}

// ---------------------------------------------------------------------------
// Kernel 2: fused VQ. R23 = EXACT R20 (session best: 65.15 us total, absmax
// 0.0) -- LOCK-IN. Counted-vmcnt 2-deep pipeline: 16-code chunks (4 KB/wave),
// 3-buffer rotation, stage chunk i+2 at iter i; the per-chunk c2 float4 VMEM
// load is issued FIRST so its compiler wait (in-order vmcnt) retires ch_{i+1}
// but leaves ch_{i+2} in flight; explicit gates vmcnt(9)/(5)/(1) -- never a
// full drain in the loop. Session findings locked by R21/R22 single-variable
// tests: depth 3 is harmful, c2-in-LDS is neutral -> this exact config is
// the optimum of the explored family. Plus R18/R19's deduped x-prologue,
// wave-private barrier-free scan, hoisted rescore loads, fused q-store.
// vmcnt gate proof: at iter i's gate there are >=9 loads newer than chunk
// i's 4 (ch_{i+1}:4, c2_i:1, ch_{i+2}:4); in-order retirement => "<=9
// outstanding" implies chunk i landed. Tail: i=14 -> 5 newer, i=15 -> 1.
// ---------------------------------------------------------------------------
__global__ __launch_bounds__(256, 2) void vq_mfma(const float* __restrict__ x,
                                                  const float* __restrict__ cb,
                                                  const unsigned short* __restrict__ cbbf,
                                                  const float* __restrict__ c2w,
                                                  int* __restrict__ idxw,
                                                  float* __restrict__ Sw,
                                                  float* __restrict__ out) {
    __shared__ __align__(16) unsigned short cbuf[3][4][2048]; // 3 x 16 KB
    __shared__ float mbuf[4][4][16][3];                       // 3 KB
    __shared__ float nbuf[4][64];                             // 1 KB norms
    __shared__ int ibuf[64];                                  // 256 B

    const int t  = threadIdx.x;
    const int w  = t >> 6;                      // wave 0..3 = code quarter
    const int ln = t & 63;
    const int lp = ln & 15;                     // position lane (n index)
    const int q  = ln >> 4;                     // quad 0..3 (k sub-range)
    const int bid = blockIdx.x;
    const int b   = bid >> 6;                   // batch (64 blocks per image)
    const int s0  = (bid & 63) << 6;            // 64-position tile start

    // wave's quarter of the pre-swizzled bf16 codebook (64 KB)
    const char* gq = (const char*)cbbf + (w << 16);

    { // stage chunks 0,1 -> buffers 0,1 NOW; latency hides under x-prologue
        const char* gs = gq + (ln << 4);
        char* l0 = (char*)&cbuf[0][w][0];
        char* l1 = (char*)&cbuf[1][w][0];
        #pragma unroll
        for (int r = 0; r < 4; ++r) gll16(gs + r * 1024, l0 + r * 1024);
        #pragma unroll
        for (int r = 0; r < 4; ++r) gll16(gs + 4096 + r * 1024, l1 + r * 1024);
    }

    // ---- x-prologue: ONE coalesced load + convert per value, shared via
    //      LDS transpose buffer (aliases cbuf[2]; dead until chunk-2) ----
    unsigned short* xbuf = &cbuf[2][0][0];       // 64 pos x 128 ch bf16, 16 KB
    {
        float ssp = 0.f;
        const float* xgp = x + b * CHW + (w * 32) * HW + s0 + ln;
        #pragma unroll
        for (int g = 0; g < 4; ++g) {            // granule = 8 channels, 16B
            union { short8 v; unsigned short u[8]; } fu;
            #pragma unroll
            for (int j = 0; j < 8; ++j) {
                float vv = xgp[(g * 8 + j) * HW];   // 256B coalesced segment
                ssp = fmaf(vv, vv, ssp);
                fu.u[j] = f2bf(vv);
            }
            int col = (w * 4 + g) ^ (ln & 7);    // same swizzle family as cb
            *(short8*)(xbuf + ln * 128 + col * 8) = fu.v;
        }
        nbuf[w][ln] = ssp;                       // partial over w's 32 ch
    }
    __syncthreads();                             // xbuf + nbuf complete

    // norms: fixed pairwise order over the 4 wave-partials
    float r2v[4];
    #pragma unroll
    for (int pt = 0; pt < 4; ++pt) {
        const int pos = pt * 16 + lp;
        float s01 = nbuf[0][pos] + nbuf[1][pos];
        float s23 = nbuf[2][pos] + nbuf[3][pos];
        float s   = s01 + s23;
        r2v[pt] = -2.0f / fmaxf(sqrtf(s), 1e-12f);  // F.normalize eps
    }

    // fragments: identical layout/order (bit-identical bf16)
    short8 xf[4][4];
    #pragma unroll
    for (int pt = 0; pt < 4; ++pt)
        #pragma unroll
        for (int cs = 0; cs < 4; ++cs) {
            int col = (4 * cs + q) ^ (lp & 7);   // (pt*16+lp)&7 == lp&7
            xf[pt][cs] = *(const short8*)(xbuf + (pt * 16 + lp) * 128 + col * 8);
        }
    asm volatile("s_waitcnt lgkmcnt(0)" ::: "memory");  // xf live in regs
    __builtin_amdgcn_sched_barrier(0);
    __syncthreads();                             // xbuf (buf 2) free for ch2

    const float FMAX = __uint_as_float(0x7F7FFFFFu);
    float m1[4] = {FMAX, FMAX, FMAX, FMAX};
    float m2[4] = {FMAX, FMAX, FMAX, FMAX};
    float m3[4] = {FMAX, FMAX, FMAX, FMAX};

    for (int i = 0; i < 16; ++i) {              // 16 chunks x 16 codes
        const int k0 = (w << 8) + (i << 4);
        // c2 first: its compiler-inserted wait retires ch_{i+1} (older) but
        // leaves ch_{i+2} (newer) in flight -- no full drain.
        float4 c2vv = *(const float4*)(c2w + k0 + 4 * q);

        if (i < 14) {                            // stage chunk i+2 (private)
            asm volatile("s_waitcnt lgkmcnt(0)" ::: "memory");
            const char* gs = gq + (i + 2) * 4096 + (ln << 4);
            char* ld = (char*)&cbuf[(i + 2) % 3][w][0];
            #pragma unroll
            for (int r = 0; r < 4; ++r) gll16(gs + r * 1024, ld + r * 1024);
        }

        // counted gate: chunk i landed; ch_{i+1}/c2/ch_{i+2} stay in flight
        if (i < 14)       asm volatile("s_waitcnt vmcnt(9)" ::: "memory");
        else if (i == 14) asm volatile("s_waitcnt vmcnt(5)" ::: "memory");
        else              asm volatile("s_waitcnt vmcnt(1)" ::: "memory");
        __builtin_amdgcn_sched_barrier(0);

        const unsigned short* cbp = &cbuf[i % 3][w][0];

        f32x4 acc[4];
        #pragma unroll
        for (int pt = 0; pt < 4; ++pt) acc[pt] = 0;

        #pragma unroll
        for (int cs = 0; cs < 4; ++cs) {
            // A[m=lp][k=32cs+8q+j]; row-within-chunk = lp, swizzled granule
            int g = lp * 16 + ((4 * cs + q) ^ (lp & 7));
            short8 ah = *(const short8*)(cbp + g * 8);
            #pragma unroll
            for (int pt = 0; pt < 4; ++pt)
                acc[pt] = __builtin_amdgcn_mfma_f32_16x16x32_bf16(
                    ah, xf[pt][cs], acc[pt], 0, 0, 0);
        }

        // ---- epilogue: 16 scores/lane (4pt x 4reg) -- R14-verified math ----
        {
            float c2a[4] = {c2vv.x, c2vv.y, c2vv.z, c2vv.w};
            const int kb0 = k0 + 4 * q;
            #pragma unroll
            for (int pt = 0; pt < 4; ++pt) {
                #pragma unroll
                for (int reg = 0; reg < 4; ++reg) {
                    float s = fmaf(r2v[pt], acc[pt][reg], c2a[reg]);
                    unsigned pb = (__float_as_uint(s) & 0xFFFFFC00u) |
                                  (unsigned)(kb0 + reg);
                    float u  = __uint_as_float(pb);
                    float t3 = __builtin_amdgcn_fmed3f(m2[pt], m3[pt], u);
                    float t2 = __builtin_amdgcn_fmed3f(m1[pt], m2[pt], u);
                    m1[pt] = fminf(m1[pt], u); m2[pt] = t2; m3[pt] = t3;
                }
            }
        }
    }

    // ---- merge chains across the 4 quad-lanes (butterfly, all 4 pt) ----
    #pragma unroll
    for (int d = 16; d <= 32; d <<= 1) {
        #pragma unroll
        for (int pt = 0; pt < 4; ++pt) {
            float o1 = __shfl_xor(m1[pt], d), o2 = __shfl_xor(m2[pt], d),
                  o3 = __shfl_xor(m3[pt], d);
            float u, t2, t3;
            u = o1; t3 = __builtin_amdgcn_fmed3f(m2[pt], m3[pt], u);
            t2 = __builtin_amdgcn_fmed3f(m1[pt], m2[pt], u);
            m1[pt] = fminf(m1[pt], u); m2[pt] = t2; m3[pt] = t3;
            u = o2; t3 = __builtin_amdgcn_fmed3f(m2[pt], m3[pt], u);
            t2 = __builtin_amdgcn_fmed3f(m1[pt], m2[pt], u);
            m1[pt] = fminf(m1[pt], u); m2[pt] = t2; m3[pt] = t3;
            u = o3; t3 = __builtin_amdgcn_fmed3f(m2[pt], m3[pt], u);
            t2 = __builtin_amdgcn_fmed3f(m1[pt], m2[pt], u);
            m1[pt] = fminf(m1[pt], u); m2[pt] = t2; m3[pt] = t3;
        }
    }

    // publish all 4 per-quarter chains
    if (ln < 16) {
        #pragma unroll
        for (int pt = 0; pt < 4; ++pt) {
            mbuf[w][pt][lp][0] = m1[pt];
            mbuf[w][pt][lp][1] = m2[pt];
            mbuf[w][pt][lp][2] = m3[pt];
        }
    }

    // ---- hoisted rescore x-reload (bit-identical; hides under barrier) ----
    float xr2[2][32];
    if (w < 2) {
        #pragma unroll
        for (int ptl = 0; ptl < 2; ++ptl) {
            const int pt = 2 * w + ptl;
            const float* xgp = x + b * CHW + s0 + pt * 16 + lp;
            #pragma unroll
            for (int cs = 0; cs < 4; ++cs)
                #pragma unroll
                for (int j = 0; j < 8; ++j)
                    xr2[ptl][cs * 8 + j] = xgp[(32 * cs + 8 * q + j) * HW];
        }
    }
    __syncthreads();

    // ---- rescore: wave 0 -> positions 0-31 (pt 0,1), wave 1 -> 32-63 ----
    if (w < 2) {
        float lsum = 0.f;
        #pragma unroll
        for (int ptl = 0; ptl < 2; ++ptl) {
            const int pt = 2 * w + ptl;
            // merge the 4 quarters' chains (fixed order; unique top-3 set)
            float M1 = FMAX, M2 = FMAX, M3 = FMAX;
            #pragma unroll
            for (int ww = 0; ww < 4; ++ww)
                #pragma unroll
                for (int c = 0; c < 3; ++c) {
                    float u  = mbuf[ww][pt][lp][c];
                    float t3 = __builtin_amdgcn_fmed3f(M2, M3, u);
                    float t2 = __builtin_amdgcn_fmed3f(M1, M2, u);
                    M1 = fminf(M1, u); M2 = t2; M3 = t3;
                }
            int ks[3] = {(int)(__float_as_uint(M1) & 1023u),
                         (int)(__float_as_uint(M2) & 1023u),
                         (int)(__float_as_uint(M3) & 1023u)};

            const float* xr = xr2[ptl];          // preloaded, bit-identical

            // exact fp32 rescore of the 3 candidates (same order as R4-R22)
            float dots[3];
            #pragma unroll
            for (int jj = 0; jj < 3; ++jj) {
                const float* crow = cb + ks[jj] * C_DIM + 8 * q;
                float p = 0.f;
                #pragma unroll
                for (int cs = 0; cs < 4; ++cs) {
                    float4 a0 = *(const float4*)(crow + 32 * cs);
                    float4 a1 = *(const float4*)(crow + 32 * cs + 4);
                    p = fmaf(xr[cs*8+0], a0.x, p); p = fmaf(xr[cs*8+1], a0.y, p);
                    p = fmaf(xr[cs*8+2], a0.z, p); p = fmaf(xr[cs*8+3], a0.w, p);
                    p = fmaf(xr[cs*8+4], a1.x, p); p = fmaf(xr[cs*8+5], a1.y, p);
                    p = fmaf(xr[cs*8+6], a1.z, p); p = fmaf(xr[cs*8+7], a1.w, p);
                }
                p += __shfl_xor(p, 16);
                p += __shfl_xor(p, 32);
                dots[jj] = p;
            }
            float sb = fmaf(r2v[pt], dots[0], c2w[ks[0]]); int kb = ks[0];
            float s2 = fmaf(r2v[pt], dots[1], c2w[ks[1]]);
            if (s2 < sb || (s2 == sb && ks[1] < kb)) { sb = s2; kb = ks[1]; }
            float s3 = fmaf(r2v[pt], dots[2], c2w[ks[2]]);
            if (s3 < sb || (s3 == sb && ks[2] < kb)) { sb = s3; kb = ks[2]; }

            if (ln < 16) {
                idxw[bid * 64 + pt * 16 + lp] = kb;
                ibuf[pt * 16 + lp] = kb;         // publish for fused store
            }
            lsum += sqrtf(fmaxf(1.0f + sb, 0.f));   // z2 == 1 after normalize
        }
        // each position counted by its 4 q-lanes -> scale 0.25
        #pragma unroll
        for (int off = 32; off > 0; off >>= 1) lsum += __shfl_down(lsum, off);
        if (ln == 0) atomicAdd(Sw, 0.25f * lsum);
    }

    // ---- fused q-store (b>0; batch 0's region aliases cbbf -> write_q0) ----
    __syncthreads();                             // ibuf visible to all waves
    if (b != 0) {
        const int row = ibuf[ln];                // position s0+ln's code
        const float4* cbr = (const float4*)cb + row * 32;
        float* ob = out + b * CHW + s0 + ln;
        #pragma unroll
        for (int c4 = w * 8; c4 < w * 8 + 8; ++c4) {   // wave w: 32 channels
            float4 v = cbr[c4];                  // 16B gather, L2-hot
            float* o = ob + (c4 * 4) * HW;
            o[0]      = v.x;                     // each store: 64 lanes x 4B
            o[HW]     = v.y;                     //  = coalesced 256B segment
            o[2 * HW] = v.z;
            o[3 * HW] = v.w;
        }
    }
}

// ---------------------------------------------------------------------------
// Kernel 3: batch-0 scatter (region was cbbf scratch during vq) + losses.
// ---------------------------------------------------------------------------
__global__ void write_q0(const float* __restrict__ cb,
                         const int* __restrict__ idxw,
                         const float* __restrict__ ws,
                         float* __restrict__ out) {
    int id = blockIdx.x * 256 + threadIdx.x;   // 131072 = 4096 * 32
    int s  = id & 4095;                        // spatial (lanes consecutive)
    int c4 = id >> 12;                         // channel quad 0..31
    int row = idxw[s];                         // batch 0 -> p == s
    float4 v = ((const float4*)cb)[row * 32 + c4];   // 16B gather, L2-hot
    float* o = out + (c4 * 4) * HW + s;        // b = 0
    o[0]      = v.x;
    o[HW]     = v.y;
    o[2 * HW] = v.z;
    o[3 * HW] = v.w;
    if (id == 0) {                             // loss finalize (after vq)
        float S = *(const float*)((const char*)ws + WS_S);
        float m = S / (float)N_POS;
        out[Q_ELEMS]     = 0.25f * m;
        out[Q_ELEMS + 1] = m;
    }
}

extern "C" void kernel_launch(void* const* d_in, const int* in_sizes, int n_in,
                              void* d_out, int out_size, void* d_ws, size_t ws_size,
                              hipStream_t stream) {
    const float* x  = (const float*)d_in[0];   // [16,128,64,64]
    const float* cb = (const float*)d_in[1];   // [1024,128]
    float* out = (float*)d_out;
    float* ws  = (float*)d_ws;

    const float* c2w = (const float*)((const char*)d_ws + WS_C2);
    int*  idxw = (int*)((char*)d_ws + WS_IDX);
    float* Sw  = (float*)((char*)d_ws + WS_S);
    unsigned short* cbbf = (unsigned short*)d_out;   // scratch in d_out

    prep_kernel<<<K_CODES / 4, 256, 0, stream>>>(cb, ws, cbbf);
    vq_mfma    <<<N_POS / 64, 256, 0, stream>>>(x, cb, cbbf, c2w, idxw, Sw, out);
    write_q0   <<<512, 256, 0, stream>>>(cb, idxw, ws, out);
}